// Round 1
// baseline (18974.806 us; speedup 1.0000x reference)
//
#include <hip/hip_runtime.h>
#include <math.h>

// Problem constants (from reference setup_inputs)
#define S_LEN 1024
#define BATCH 2048
#define HID   128
#define TILE_B 8
#define NBLK  (BATCH / TILE_B)   // 256 blocks, one per CU

// Workspace layout (float offsets)
#define OFF_WSPK   0            // [128][128]  W1x[:,2:130]
#define OFF_WTAU   16384        // [128][128][4] (WdM, WmM, WdA, WbA) interleaved
#define OFF_WX0    81920        // [128]
#define OFF_WX1    82048        // [128]
#define OFF_B1X    82176        // [128]
#define OFF_BTM    82304        // [128]
#define OFF_BTA    82432        // [128]
#define OFF_WLIN   82560        // [128]
#define OFF_BLIN   82688        // [1]
#define OFF_PART   82696        // [256] per-block loss partials

__global__ __launch_bounds__(256) void prep_weights(
    const float* __restrict__ W1x, const float* __restrict__ b1x,
    const float* __restrict__ WtauM, const float* __restrict__ btauM,
    const float* __restrict__ WtauAdp, const float* __restrict__ btauAdp,
    const float* __restrict__ Wlin, const float* __restrict__ blin,
    float* __restrict__ ws) {
  int idx = blockIdx.x * 256 + threadIdx.x;   // 64 blocks x 256 = 16384
  int h = idx >> 7;
  int k = idx & 127;
  // spk part of W1x (columns 2..129), packed contiguous per h-row
  ws[OFF_WSPK + idx] = W1x[h * 130 + 2 + k];
  // tau weights interleaved: one float4 per (h,k)
  float4 wt;
  wt.x = WtauM[h * 256 + k];          // dense -> tauM
  wt.y = WtauM[h * 256 + 128 + k];    // mem   -> tauM
  wt.z = WtauAdp[h * 256 + k];        // dense -> tauA
  wt.w = WtauAdp[h * 256 + 128 + k];  // bb    -> tauA
  *(float4*)&ws[OFF_WTAU + idx * 4] = wt;
  if (k == 0) {
    ws[OFF_WX0 + h] = W1x[h * 130 + 0];
    ws[OFF_WX1 + h] = W1x[h * 130 + 1];
    ws[OFF_B1X + h] = b1x[h];
    ws[OFF_BTM + h] = btauM[h];
    ws[OFF_BTA + h] = btauAdp[h];
    ws[OFF_WLIN + h] = Wlin[h];
  }
  if (idx == 0) ws[OFF_BLIN] = blin[0];
}

__global__ __launch_bounds__(256) void snn_main(
    const float* __restrict__ x, const float* __restrict__ y,
    const float* __restrict__ h0m, const float* __restrict__ h0s,
    const float* __restrict__ h0b,
    const float* __restrict__ ws, float* __restrict__ wsout) {
  // Transposed state tiles: [k][tb] so matmul reads are lane-broadcast b128
  __shared__ float spkT[HID][TILE_B];
  __shared__ float memT[HID][TILE_B];
  __shared__ float bbT[HID][TILE_B];
  __shared__ float denT[HID][TILE_B];
  __shared__ float red[TILE_B];

  const int tid  = threadIdx.x;
  const int h    = tid & 127;
  const int pair = tid >> 7;          // 0 or 1
  const int tb0  = pair * 4;          // this thread handles tb0..tb0+3
  const int bbase = blockIdx.x * TILE_B;

  const float* __restrict__ Wspk  = ws + OFF_WSPK + h * 128;
  const float4* __restrict__ Wtau = (const float4*)(ws + OFF_WTAU) + h * 128;
  const float wx0 = ws[OFF_WX0 + h];
  const float wx1 = ws[OFF_WX1 + h];
  const float b1  = ws[OFF_B1X + h];
  const float btm = ws[OFF_BTM + h];
  const float bta = ws[OFF_BTA + h];

  // Per-thread recurrent state: (h, tb0..tb0+3)
  float mem[4], spk[4], bbv[4], den[4];
#pragma unroll
  for (int j = 0; j < 4; ++j) {
    int b = bbase + tb0 + j;
    mem[j] = h0m[b * HID + h];
    spk[j] = h0s[b * HID + h];
    bbv[j] = h0b[b * HID + h];
  }
  *(float4*)&spkT[h][tb0] = make_float4(spk[0], spk[1], spk[2], spk[3]);
  *(float4*)&memT[h][tb0] = make_float4(mem[0], mem[1], mem[2], mem[3]);
  *(float4*)&bbT[h][tb0]  = make_float4(bbv[0], bbv[1], bbv[2], bbv[3]);
  __syncthreads();

  for (int t = 0; t < S_LEN; ++t) {
    // ---- Phase 1: dense = [x_t, spk] @ W1x.T + b1x ----
    const float* __restrict__ xt = x + ((size_t)t * BATCH + bbase) * 2;
    float acc[4];
#pragma unroll
    for (int j = 0; j < 4; ++j) {
      float2 xv = *(const float2*)&xt[(tb0 + j) * 2];
      acc[j] = b1 + xv.x * wx0 + xv.y * wx1;
    }
#pragma unroll 4
    for (int k = 0; k < 128; k += 4) {
      float4 w  = *(const float4*)&Wspk[k];
      float4 s0 = *(const float4*)&spkT[k + 0][tb0];
      float4 s1 = *(const float4*)&spkT[k + 1][tb0];
      float4 s2 = *(const float4*)&spkT[k + 2][tb0];
      float4 s3 = *(const float4*)&spkT[k + 3][tb0];
      acc[0] += w.x * s0.x + w.y * s1.x + w.z * s2.x + w.w * s3.x;
      acc[1] += w.x * s0.y + w.y * s1.y + w.z * s2.y + w.w * s3.y;
      acc[2] += w.x * s0.z + w.y * s1.z + w.z * s2.z + w.w * s3.z;
      acc[3] += w.x * s0.w + w.y * s1.w + w.z * s2.w + w.w * s3.w;
    }
#pragma unroll
    for (int j = 0; j < 4; ++j) den[j] = acc[j];
    *(float4*)&denT[h][tb0] = make_float4(acc[0], acc[1], acc[2], acc[3]);
    __syncthreads();

    // ---- Phase 2: tauM = sig([dense,mem]@WtauM.T + b), tauA with bb ----
    float accM[4], accA[4];
#pragma unroll
    for (int j = 0; j < 4; ++j) { accM[j] = btm; accA[j] = bta; }
#pragma unroll 4
    for (int k = 0; k < 128; ++k) {
      float4 wt = Wtau[k];                         // (WdM, WmM, WdA, WbA)
      float4 dv = *(const float4*)&denT[k][tb0];
      float4 mv = *(const float4*)&memT[k][tb0];
      float4 bv = *(const float4*)&bbT[k][tb0];
      accM[0] += wt.x * dv.x + wt.y * mv.x;
      accA[0] += wt.z * dv.x + wt.w * bv.x;
      accM[1] += wt.x * dv.y + wt.y * mv.y;
      accA[1] += wt.z * dv.y + wt.w * bv.y;
      accM[2] += wt.x * dv.z + wt.y * mv.z;
      accA[2] += wt.z * dv.z + wt.w * bv.z;
      accM[3] += wt.x * dv.w + wt.y * mv.w;
      accA[3] += wt.z * dv.w + wt.w * bv.w;
    }
    __syncthreads();   // all reads of memT/bbT/denT/spkT done

    // ---- Phase 3: elementwise state update ----
#pragma unroll
    for (int j = 0; j < 4; ++j) {
      float tM = 1.0f / (1.0f + __expf(-accM[j]));
      float tA = 1.0f / (1.0f + __expf(-accA[j]));
      bbv[j] = tA * bbv[j] + (1.0f - tA) * spk[j];
      float Bth = 0.01f + 1.8f * bbv[j];
      mem[j] = mem[j] * tM + (1.0f - tM) * den[j] - Bth * spk[j];
      spk[j] = (mem[j] - Bth) > 0.0f ? 1.0f : 0.0f;
    }
    *(float4*)&spkT[h][tb0] = make_float4(spk[0], spk[1], spk[2], spk[3]);
    *(float4*)&memT[h][tb0] = make_float4(mem[0], mem[1], mem[2], mem[3]);
    *(float4*)&bbT[h][tb0]  = make_float4(bbv[0], bbv[1], bbv[2], bbv[3]);
    __syncthreads();
  }

  // ---- Readout: out[b] = mem[b,:] @ Wlin + blin; partial loss per block ----
  const float wlin = ws[OFF_WLIN + h];
  *(float4*)&denT[h][tb0] = make_float4(mem[0] * wlin, mem[1] * wlin,
                                        mem[2] * wlin, mem[3] * wlin);
  __syncthreads();
  if (tid < TILE_B) {
    float s = 0.0f;
    for (int hh = 0; hh < HID; ++hh) s += denT[hh][tid];
    float out = s + ws[OFF_BLIN];
    float d = out - y[bbase + tid];
    red[tid] = d * d;
  }
  __syncthreads();
  if (tid == 0) {
    float p = 0.0f;
#pragma unroll
    for (int j = 0; j < TILE_B; ++j) p += red[j];
    wsout[OFF_PART + blockIdx.x] = p;
  }
}

__global__ __launch_bounds__(256) void final_reduce(const float* __restrict__ ws,
                                                    float* __restrict__ out) {
  __shared__ float sh[256];
  int t = threadIdx.x;
  sh[t] = ws[OFF_PART + t];
  __syncthreads();
  for (int s = 128; s > 0; s >>= 1) {
    if (t < s) sh[t] += sh[t + s];
    __syncthreads();
  }
  if (t == 0) out[0] = sh[0] * (1.0f / (float)BATCH);
}

extern "C" void kernel_launch(void* const* d_in, const int* in_sizes, int n_in,
                              void* d_out, int out_size, void* d_ws, size_t ws_size,
                              hipStream_t stream) {
  const float* x       = (const float*)d_in[0];
  const float* y       = (const float*)d_in[1];
  const float* h0m     = (const float*)d_in[2];
  const float* h0s     = (const float*)d_in[3];
  const float* h0b     = (const float*)d_in[4];
  const float* W1x     = (const float*)d_in[5];
  const float* b1x     = (const float*)d_in[6];
  const float* WtauM   = (const float*)d_in[7];
  const float* btauM   = (const float*)d_in[8];
  const float* WtauAdp = (const float*)d_in[9];
  const float* btauAdp = (const float*)d_in[10];
  const float* Wlin    = (const float*)d_in[11];
  const float* blin    = (const float*)d_in[12];
  float* ws = (float*)d_ws;

  prep_weights<<<64, 256, 0, stream>>>(W1x, b1x, WtauM, btauM, WtauAdp, btauAdp,
                                       Wlin, blin, ws);
  snn_main<<<NBLK, 256, 0, stream>>>(x, y, h0m, h0s, h0b, ws, ws);
  final_reduce<<<1, 256, 0, stream>>>(ws, (float*)d_out);
}

// Round 2
// 2717.400 us; speedup vs baseline: 6.9827x; 6.9827x over previous
//
#include <hip/hip_runtime.h>
#include <math.h>

#define S_LEN 1024
#define BATCH 2048
#define HID   128
#define MTILE 16
#define NBLK  (BATCH / MTILE)   // 128 blocks
#define RS    136               // padded plane row stride (f16 elems): 128 + 8
#define PLANE (MTILE * RS)      // 2176 elems per plane
#define INV2048 (1.0f / 2048.0f)

typedef _Float16 half8 __attribute__((ext_vector_type(8)));
typedef float floatx4 __attribute__((ext_vector_type(4)));

#define MFMA(a, b, c) __builtin_amdgcn_mfma_f32_16x16x32_f16((a), (b), (c), 0, 0, 0)

struct SLds {
  _Float16 spkP[2][PLANE];     // spk is exactly representable in f16: hi only
  _Float16 denH[PLANE];        // dense, single-buffered (barrier-separated)
  _Float16 denL[PLANE];
  _Float16 memH[2][PLANE];     // [buf][...]
  _Float16 memL[2][PLANE];
  _Float16 bbH[2][PLANE];
  _Float16 bbL[2][PLANE];
  float2 xst[2][16];           // staged x_t tile, double-buffered
  float   redbuf[8][16];
  float   red2[16];
};

__global__ __launch_bounds__(512) void snn_main(
    const float* __restrict__ x, const float* __restrict__ y,
    const float* __restrict__ h0m, const float* __restrict__ h0s,
    const float* __restrict__ h0b,
    const float* __restrict__ W1x, const float* __restrict__ b1x,
    const float* __restrict__ WtauM, const float* __restrict__ btauM,
    const float* __restrict__ WtauAdp, const float* __restrict__ btauAdp,
    const float* __restrict__ Wlin, const float* __restrict__ blin,
    float* __restrict__ wsout) {
  __shared__ SLds sm;

  const int tid  = threadIdx.x;
  const int w    = tid >> 6;        // wave 0..7: owns h-slice [16w, 16w+16)
  const int lane = tid & 63;
  const int c    = lane & 15;       // col within 16 (h within slice; also m for A-reads)
  const int q    = lane >> 4;       // quad 0..3
  const int hIdx = w * 16 + c;      // this lane's h (for B-frags / C-layout)
  const int bbase = blockIdx.x * MTILE;

  // ---- One-time: load weights into register-resident f16 hi/lo B-fragments.
  // B-frag layout (16x16x32): lane holds B[k = q*8 + j][n = lane&15], j=0..7.
  // lo planes pre-scaled by 2048 so values stay in f16 normal range.
  half8 w1h[4], w1l[4], wtmh[8], wtml[8], wtah[8], wtal[8];
#pragma unroll
  for (int f = 0; f < 4; ++f) {
#pragma unroll
    for (int j = 0; j < 8; ++j) {
      int k = f * 32 + q * 8 + j;
      float v = W1x[hIdx * 130 + 2 + k];      // spk columns of W1x
      _Float16 hi = (_Float16)v;
      w1h[f][j] = hi;
      w1l[f][j] = (_Float16)((v - (float)hi) * 2048.0f);
    }
  }
#pragma unroll
  for (int f = 0; f < 8; ++f) {
#pragma unroll
    for (int j = 0; j < 8; ++j) {
      int k = f * 32 + q * 8 + j;
      float vm = WtauM[hIdx * 256 + k];
      _Float16 hm = (_Float16)vm;
      wtmh[f][j] = hm;
      wtml[f][j] = (_Float16)((vm - (float)hm) * 2048.0f);
      float va = WtauAdp[hIdx * 256 + k];
      _Float16 ha = (_Float16)va;
      wtah[f][j] = ha;
      wtal[f][j] = (_Float16)((va - (float)ha) * 2048.0f);
    }
  }

  // Per-lane h scalars
  const float wx0  = W1x[hIdx * 130 + 0];
  const float wx1  = W1x[hIdx * 130 + 1];
  const float b1v  = b1x[hIdx];
  const float btmv = btauM[hIdx];
  const float btav = btauAdp[hIdx];
  const float wlinv = Wlin[hIdx];

  // ---- Initial state: registers in C-layout (m = q*4+r, h = hIdx), mirror to planes buf 0
  float memv[4], spk[4], bb[4];
#pragma unroll
  for (int r = 0; r < 4; ++r) {
    int b = bbase + q * 4 + r;
    memv[r] = h0m[b * HID + hIdx];
    spk[r]  = h0s[b * HID + hIdx];
    bb[r]   = h0b[b * HID + hIdx];
    int off = (q * 4 + r) * RS + hIdx;
    sm.spkP[0][off] = (_Float16)spk[r];
    float v = memv[r]; _Float16 hi = (_Float16)v;
    sm.memH[0][off] = hi; sm.memL[0][off] = (_Float16)((v - (float)hi) * 2048.0f);
    v = bb[r]; hi = (_Float16)v;
    sm.bbH[0][off] = hi;  sm.bbL[0][off]  = (_Float16)((v - (float)hi) * 2048.0f);
  }
  if (tid < 16)
    sm.xst[0][tid] = *(const float2*)&x[((size_t)0 * BATCH + bbase + tid) * 2];
  __syncthreads();

#pragma unroll 1
  for (int t = 0; t < S_LEN; ++t) {
    const int p = t & 1;
    const int aBase = c * RS + q * 8;   // A-frag base: m=c, k-chunk=q

    // ---- GEMM1: dense = spk @ W1x_spk^T  (spk exact in f16 -> 2-term)
    floatx4 dhh = {0.f, 0.f, 0.f, 0.f}, dll = {0.f, 0.f, 0.f, 0.f};
    const _Float16* sp = sm.spkP[p];
#pragma unroll
    for (int f = 0; f < 4; ++f) {
      half8 a = *(const half8*)&sp[aBase + f * 32];
      dhh = MFMA(a, w1h[f], dhh);
      dll = MFMA(a, w1l[f], dll);
    }
    float dense[4];
#pragma unroll
    for (int r = 0; r < 4; ++r) {
      float2 xv = sm.xst[p][q * 4 + r];
      dense[r] = dhh[r] + dll[r] * INV2048 + b1v + xv.x * wx0 + xv.y * wx1;
    }
    // write dense hi/lo planes (C-layout scatter, b16 writes)
#pragma unroll
    for (int r = 0; r < 4; ++r) {
      int off = (q * 4 + r) * RS + hIdx;
      float v = dense[r]; _Float16 hi = (_Float16)v;
      sm.denH[off] = hi;
      sm.denL[off] = (_Float16)((v - (float)hi) * 2048.0f);
    }
    // prefetch next x tile (latency hidden across GEMM2)
    float2 xnext;
    const bool doX = (tid < 16) && (t + 1 < S_LEN);
    if (doX)
      xnext = *(const float2*)&x[((size_t)(t + 1) * BATCH + bbase + tid) * 2];
    __syncthreads();

    // ---- GEMM2: accM = [dense|mem_old] @ WtauM^T ; accA = [dense|bb_old] @ WtauAdp^T
    floatx4 mhh = {0.f,0.f,0.f,0.f}, mll = {0.f,0.f,0.f,0.f};
    floatx4 ahh = {0.f,0.f,0.f,0.f}, all_ = {0.f,0.f,0.f,0.f};
#pragma unroll
    for (int f = 0; f < 8; ++f) {
      int aoff = aBase + ((f < 4) ? f : (f - 4)) * 32;
      half8 a1h, a1l, a2h, a2l;
      if (f < 4) {
        a1h = *(const half8*)&sm.denH[aoff];
        a1l = *(const half8*)&sm.denL[aoff];
        a2h = a1h; a2l = a1l;
      } else {
        a1h = *(const half8*)&sm.memH[p][aoff];
        a1l = *(const half8*)&sm.memL[p][aoff];
        a2h = *(const half8*)&sm.bbH[p][aoff];
        a2l = *(const half8*)&sm.bbL[p][aoff];
      }
      mhh  = MFMA(a1h, wtmh[f], mhh);
      mll  = MFMA(a1h, wtml[f], mll);
      mll  = MFMA(a1l, wtmh[f], mll);
      ahh  = MFMA(a2h, wtah[f], ahh);
      all_ = MFMA(a2h, wtal[f], all_);
      all_ = MFMA(a2l, wtah[f], all_);
    }

    // ---- Elementwise update (fp32, C-layout registers)
    const int pn = p ^ 1;
#pragma unroll
    for (int r = 0; r < 4; ++r) {
      float preM = mhh[r] + mll[r] * INV2048 + btmv;
      float preA = ahh[r] + all_[r] * INV2048 + btav;
      float tM = 1.0f / (1.0f + __expf(-preM));
      float tA = 1.0f / (1.0f + __expf(-preA));
      bb[r] = tA * bb[r] + (1.0f - tA) * spk[r];
      float Bth = 0.01f + 1.8f * bb[r];
      memv[r] = memv[r] * tM + (1.0f - tM) * dense[r] - Bth * spk[r];
      spk[r] = (memv[r] - Bth) > 0.0f ? 1.0f : 0.0f;

      int off = (q * 4 + r) * RS + hIdx;
      sm.spkP[pn][off] = (_Float16)spk[r];
      float v = memv[r]; _Float16 hi = (_Float16)v;
      sm.memH[pn][off] = hi; sm.memL[pn][off] = (_Float16)((v - (float)hi) * 2048.0f);
      v = bb[r]; hi = (_Float16)v;
      sm.bbH[pn][off] = hi;  sm.bbL[pn][off]  = (_Float16)((v - (float)hi) * 2048.0f);
    }
    if (doX) sm.xst[(t + 1) & 1][tid] = xnext;
    __syncthreads();
  }

  // ---- Readout: out[b] = mem[b,:] @ Wlin + blin ; per-block loss partial
  float part[4];
#pragma unroll
  for (int r = 0; r < 4; ++r) part[r] = memv[r] * wlinv;
#pragma unroll
  for (int mask = 1; mask < 16; mask <<= 1) {
#pragma unroll
    for (int r = 0; r < 4; ++r) part[r] += __shfl_xor(part[r], mask);
  }
  if (c == 0) {
#pragma unroll
    for (int r = 0; r < 4; ++r) sm.redbuf[w][q * 4 + r] = part[r];
  }
  __syncthreads();
  if (tid < 16) {
    float s = 0.0f;
#pragma unroll
    for (int ww = 0; ww < 8; ++ww) s += sm.redbuf[ww][tid];
    float out = s + blin[0];
    float d = out - y[bbase + tid];
    sm.red2[tid] = d * d;
  }
  __syncthreads();
  if (tid == 0) {
    float s = 0.0f;
#pragma unroll
    for (int m = 0; m < 16; ++m) s += sm.red2[m];
    wsout[blockIdx.x] = s;
  }
}

__global__ __launch_bounds__(128) void final_reduce(const float* __restrict__ ws,
                                                    float* __restrict__ out) {
  __shared__ float sh[128];
  int t = threadIdx.x;
  sh[t] = ws[t];
  __syncthreads();
  for (int s = 64; s > 0; s >>= 1) {
    if (t < s) sh[t] += sh[t + s];
    __syncthreads();
  }
  if (t == 0) out[0] = sh[0] * (1.0f / (float)BATCH);
}

extern "C" void kernel_launch(void* const* d_in, const int* in_sizes, int n_in,
                              void* d_out, int out_size, void* d_ws, size_t ws_size,
                              hipStream_t stream) {
  const float* x       = (const float*)d_in[0];
  const float* y       = (const float*)d_in[1];
  const float* h0m     = (const float*)d_in[2];
  const float* h0s     = (const float*)d_in[3];
  const float* h0b     = (const float*)d_in[4];
  const float* W1x     = (const float*)d_in[5];
  const float* b1x     = (const float*)d_in[6];
  const float* WtauM   = (const float*)d_in[7];
  const float* btauM   = (const float*)d_in[8];
  const float* WtauAdp = (const float*)d_in[9];
  const float* btauAdp = (const float*)d_in[10];
  const float* Wlin    = (const float*)d_in[11];
  const float* blin    = (const float*)d_in[12];
  float* ws = (float*)d_ws;

  snn_main<<<NBLK, 512, 0, stream>>>(x, y, h0m, h0s, h0b, W1x, b1x,
                                     WtauM, btauM, WtauAdp, btauAdp,
                                     Wlin, blin, ws);
  final_reduce<<<1, 128, 0, stream>>>(ws, (float*)d_out);
}